// Round 6
// baseline (279.936 us; speedup 1.0000x reference)
//
#include <hip/hip_runtime.h>

// ---- constants for B=4, S=2048, D=768, H=12, HD=64 ----
#define BB 4
#define SS 2048
#define DD 768
#define HH 12
#define HDD 64
#define BS (BB*SS)            // 8192 rows
#define NQKV (3*DD)           // 2304
#define NEL (BS*DD)           // 6291456

#define NB_PACK 6144          // NEL/4/256
#define NB_TQKV 1728          // (2304/32)*(768/32)
#define NB_TPRJ 576           // (768/32)*(768/32)

typedef __attribute__((ext_vector_type(8))) __bf16 bf16x8;
typedef __attribute__((ext_vector_type(4))) float fx4;
typedef __attribute__((ext_vector_type(4))) int   ix4;

#define MFMA16(a,b,c) __builtin_amdgcn_mfma_f32_16x16x32_bf16((a),(b),(c),0,0,0)

__device__ __forceinline__ unsigned short f2bf(float f) {
  unsigned u = __builtin_bit_cast(unsigned, f);
  u = (u + 0x7FFFu + ((u >> 16) & 1u)) >> 16;
  return (unsigned short)u;
}
// pack two fp32 -> bf16 pair
__device__ __forceinline__ unsigned pkbf(float a, float b) {
  unsigned ua = __builtin_bit_cast(unsigned, a);
  unsigned ub = __builtin_bit_cast(unsigned, b);
  return ((ua + 0x8000u) >> 16) | ((ub + 0x8000u) & 0xFFFF0000u);
}

// ---- merged prep: pack ctx->bf16 AND transpose both weights (1 launch) ----
__global__ __launch_bounds__(256) void prep_k(const float* __restrict__ ctx,
                                              unsigned short* __restrict__ Xbf,
                                              const float* __restrict__ wqkv,
                                              unsigned short* __restrict__ WqkvT,
                                              const float* __restrict__ wproj,
                                              unsigned short* __restrict__ WprojT) {
  const int bid = blockIdx.x;
  const int tid = threadIdx.x;
  if (bid < NB_PACK) {
    int i = bid * 256 + tid;
    float4 v = ((const float4*)ctx)[i];
    ((uint2*)Xbf)[i] = make_uint2(pkbf(v.x, v.y), pkbf(v.z, v.w));
    return;
  }
  __shared__ unsigned short t[32][33];
  const float* w; unsigned short* wT; int N, bx, by;
  if (bid < NB_PACK + NB_TQKV) {
    int b2 = bid - NB_PACK;
    w = wqkv; wT = WqkvT; N = NQKV; bx = b2 % 72; by = b2 / 72;
  } else {
    int b3 = bid - NB_PACK - NB_TQKV;
    w = wproj; wT = WprojT; N = DD; bx = b3 % 24; by = b3 / 24;
  }
  int n0 = bx * 32, k0 = by * 32;
  int tx = tid & 31, ty = tid >> 5;
#pragma unroll
  for (int r = ty; r < 32; r += 8)
    t[tx][r] = f2bf(w[(size_t)(k0 + r) * N + n0 + tx]);
  __syncthreads();
#pragma unroll
  for (int r = ty; r < 32; r += 8)
    wT[(size_t)(n0 + r) * DD + k0 + tx] = t[r][tx];
}

// ==== QKV GEMM: C^T[feature][seq] = Wt(2304x768) x X(8192x768)^T ====
// 128x128 tile, BK=32, LDS double-buffer (1 barrier/iter), 4 waves x 64x64.
__global__ __launch_bounds__(256) void gemm_qkv_k(const unsigned short* __restrict__ Wt,
                                                  const unsigned short* __restrict__ X,
                                                  unsigned short* __restrict__ Qo,
                                                  unsigned short* __restrict__ Ko,
                                                  unsigned short* __restrict__ Vto) {
  __shared__ unsigned short As[2][128 * 32];
  __shared__ unsigned short Bs[2][128 * 32];
  const int tid = threadIdx.x;
  const int w = tid >> 6, lane = tid & 63, quad = lane >> 4, l16 = lane & 15;
  const int m0 = blockIdx.y << 7;   // feature
  const int n0 = blockIdx.x << 7;   // seq row
  const int wm = (w & 1) * 64, wn = (w >> 1) * 64;
  fx4 acc[4][4];
#pragma unroll
  for (int i = 0; i < 4; ++i)
#pragma unroll
    for (int c = 0; c < 4; ++c) acc[i][c] = (fx4){0.f, 0.f, 0.f, 0.f};

  const int c0 = tid, c1 = 256 + tid;
  const unsigned short* Ag0 = Wt + (size_t)(m0 + (c0 >> 2)) * DD + (c0 & 3) * 8;
  const unsigned short* Ag1 = Wt + (size_t)(m0 + (c1 >> 2)) * DD + (c1 & 3) * 8;
  const unsigned short* Bg0 = X + (size_t)(n0 + (c0 >> 2)) * DD + (c0 & 3) * 8;
  const unsigned short* Bg1 = X + (size_t)(n0 + (c1 >> 2)) * DD + (c1 & 3) * 8;

  ix4 ra0 = *(const ix4*)Ag0;
  ix4 ra1 = *(const ix4*)Ag1;
  ix4 rb0 = *(const ix4*)Bg0;
  ix4 rb1 = *(const ix4*)Bg1;
  *(ix4*)((char*)As[0] + c0 * 16) = ra0;
  *(ix4*)((char*)As[0] + c1 * 16) = ra1;
  *(ix4*)((char*)Bs[0] + c0 * 16) = rb0;
  *(ix4*)((char*)Bs[0] + c1 * 16) = rb1;
  __syncthreads();

  for (int k0 = 0; k0 < DD; k0 += 32) {
    const int cur = (k0 >> 5) & 1;
    const bool more = (k0 + 32 < DD);
    if (more) {
      ra0 = *(const ix4*)(Ag0 + k0 + 32);
      ra1 = *(const ix4*)(Ag1 + k0 + 32);
      rb0 = *(const ix4*)(Bg0 + k0 + 32);
      rb1 = *(const ix4*)(Bg1 + k0 + 32);
    }
    bf16x8 af[4], bf[4];
#pragma unroll
    for (int i = 0; i < 4; ++i) af[i] = *(const bf16x8*)&As[cur][(wm + i * 16 + l16) * 32 + quad * 8];
#pragma unroll
    for (int c = 0; c < 4; ++c) bf[c] = *(const bf16x8*)&Bs[cur][(wn + c * 16 + l16) * 32 + quad * 8];
#pragma unroll
    for (int i = 0; i < 4; ++i)
#pragma unroll
      for (int c = 0; c < 4; ++c) acc[i][c] = MFMA16(af[i], bf[c], acc[i][c]);
    if (more) {
      *(ix4*)((char*)As[cur ^ 1] + c0 * 16) = ra0;
      *(ix4*)((char*)As[cur ^ 1] + c1 * 16) = ra1;
      *(ix4*)((char*)Bs[cur ^ 1] + c0 * 16) = rb0;
      *(ix4*)((char*)Bs[cur ^ 1] + c1 * 16) = rb1;
    }
    __syncthreads();
  }

  const int which = m0 / DD;  // block-uniform: 0=Q 1=K 2=V (768 = 6*128, no straddle)
#pragma unroll
  for (int i = 0; i < 4; ++i) {
    int fb = m0 + wm + i * 16 + quad * 4;
    int d = fb - which * DD;
    int h = d >> 6, hd = d & 63;
#pragma unroll
    for (int c = 0; c < 4; ++c) {
      int srow = n0 + wn + c * 16 + l16;
      int b = srow >> 11, s = srow & (SS - 1);
      if (which == 0) {
        uint2 v = make_uint2(pkbf(acc[i][c][0], acc[i][c][1]), pkbf(acc[i][c][2], acc[i][c][3]));
        *(uint2*)&Qo[((size_t)(b * HH + h) * SS + s) * HDD + hd] = v;
      } else if (which == 1) {
        uint2 v = make_uint2(pkbf(acc[i][c][0], acc[i][c][1]), pkbf(acc[i][c][2], acc[i][c][3]));
        *(uint2*)&Ko[((size_t)(b * HH + h) * SS + s) * HDD + hd] = v;
      } else {
#pragma unroll
        for (int r = 0; r < 4; ++r)
          Vto[((size_t)(b * HH + h) * HDD + hd + r) * SS + s] = f2bf(acc[i][c][r]);
      }
    }
  }
}

// ==== proj GEMM: C^T[feat][seq] = WprojT(768x768) x Ao(8192x768)^T ====
// epilogue: + b_proj + residual(ctx), fp32 out (feeds LN)
__global__ __launch_bounds__(256) void gemm_proj_k(const unsigned short* __restrict__ Wt,
                                                   const unsigned short* __restrict__ X,
                                                   const float* __restrict__ ctx,
                                                   const float* __restrict__ bproj,
                                                   float* __restrict__ xf) {
  __shared__ unsigned short As[2][128 * 32];
  __shared__ unsigned short Bs[2][128 * 32];
  const int tid = threadIdx.x;
  const int w = tid >> 6, lane = tid & 63, quad = lane >> 4, l16 = lane & 15;
  const int m0 = blockIdx.y << 7;
  const int n0 = blockIdx.x << 7;
  const int wm = (w & 1) * 64, wn = (w >> 1) * 64;
  fx4 acc[4][4];
#pragma unroll
  for (int i = 0; i < 4; ++i)
#pragma unroll
    for (int c = 0; c < 4; ++c) acc[i][c] = (fx4){0.f, 0.f, 0.f, 0.f};

  const int c0 = tid, c1 = 256 + tid;
  const unsigned short* Ag0 = Wt + (size_t)(m0 + (c0 >> 2)) * DD + (c0 & 3) * 8;
  const unsigned short* Ag1 = Wt + (size_t)(m0 + (c1 >> 2)) * DD + (c1 & 3) * 8;
  const unsigned short* Bg0 = X + (size_t)(n0 + (c0 >> 2)) * DD + (c0 & 3) * 8;
  const unsigned short* Bg1 = X + (size_t)(n0 + (c1 >> 2)) * DD + (c1 & 3) * 8;

  ix4 ra0 = *(const ix4*)Ag0;
  ix4 ra1 = *(const ix4*)Ag1;
  ix4 rb0 = *(const ix4*)Bg0;
  ix4 rb1 = *(const ix4*)Bg1;
  *(ix4*)((char*)As[0] + c0 * 16) = ra0;
  *(ix4*)((char*)As[0] + c1 * 16) = ra1;
  *(ix4*)((char*)Bs[0] + c0 * 16) = rb0;
  *(ix4*)((char*)Bs[0] + c1 * 16) = rb1;
  __syncthreads();

  for (int k0 = 0; k0 < DD; k0 += 32) {
    const int cur = (k0 >> 5) & 1;
    const bool more = (k0 + 32 < DD);
    if (more) {
      ra0 = *(const ix4*)(Ag0 + k0 + 32);
      ra1 = *(const ix4*)(Ag1 + k0 + 32);
      rb0 = *(const ix4*)(Bg0 + k0 + 32);
      rb1 = *(const ix4*)(Bg1 + k0 + 32);
    }
    bf16x8 af[4], bf[4];
#pragma unroll
    for (int i = 0; i < 4; ++i) af[i] = *(const bf16x8*)&As[cur][(wm + i * 16 + l16) * 32 + quad * 8];
#pragma unroll
    for (int c = 0; c < 4; ++c) bf[c] = *(const bf16x8*)&Bs[cur][(wn + c * 16 + l16) * 32 + quad * 8];
#pragma unroll
    for (int i = 0; i < 4; ++i)
#pragma unroll
      for (int c = 0; c < 4; ++c) acc[i][c] = MFMA16(af[i], bf[c], acc[i][c]);
    if (more) {
      *(ix4*)((char*)As[cur ^ 1] + c0 * 16) = ra0;
      *(ix4*)((char*)As[cur ^ 1] + c1 * 16) = ra1;
      *(ix4*)((char*)Bs[cur ^ 1] + c0 * 16) = rb0;
      *(ix4*)((char*)Bs[cur ^ 1] + c1 * 16) = rb1;
    }
    __syncthreads();
  }

#pragma unroll
  for (int i = 0; i < 4; ++i) {
    int fb = m0 + wm + i * 16 + quad * 4;
    float4 bp = *(const float4*)&bproj[fb];
#pragma unroll
    for (int c = 0; c < 4; ++c) {
      int srow = n0 + wn + c * 16 + l16;
      float4 cx = *(const float4*)&ctx[(size_t)srow * DD + fb];
      float4 r;
      r.x = acc[i][c][0] + bp.x + cx.x;
      r.y = acc[i][c][1] + bp.y + cx.y;
      r.z = acc[i][c][2] + bp.z + cx.z;
      r.w = acc[i][c][3] + bp.w + cx.w;
      *(float4*)&xf[(size_t)srow * DD + fb] = r;
    }
  }
}

// ==== attention: S^T = K·Q^T; P in registers (k-permuted PV); LDS dbuf ====
// block = 128 q-rows x one (b,h); 4 waves x 32 q-rows; 64-key tiles, 1 barrier/tile.
__global__ __launch_bounds__(256) void attn_k(const unsigned short* __restrict__ Q,
                                              const unsigned short* __restrict__ K,
                                              const unsigned short* __restrict__ Vt,
                                              const float* __restrict__ mask,
                                              unsigned short* __restrict__ O) {
  __shared__ unsigned short Ks[2][64 * 64];   // [key][dd], 16B chunks XOR-swizzled by row&7
  __shared__ unsigned short Vts[2][64 * 64];  // [hd][key], same swizzle
  const int tid = threadIdx.x;
  const int w = tid >> 6, lane = tid & 63;
  const int quad = lane >> 4, l16 = lane & 15;
  const int bh = blockIdx.y;
  const int b = bh / HH, h = bh - b * HH;
  const int q0 = blockIdx.x << 7;
  const unsigned short* Qb = Q + (size_t)bh * (SS * HDD);
  const unsigned short* Kb = K + (size_t)bh * (SS * HDD);
  const unsigned short* Vtb = Vt + (size_t)bh * (SS * HDD);
  const float* mb = mask + b * SS;

  // softmax constants with log2e absorbed: p = exp2(s*C2 + offn), offn = (m-1)*1e10*log2e
  const float C2 = 0.125f * 1.44269504089f;
  const float OFF2 = 1.0e10f * 1.44269504089f;

  // Q fragments (B-operand: n=q=l16, k=dd natural)
  bf16x8 qf[2][2];
#pragma unroll
  for (int qi = 0; qi < 2; ++qi)
#pragma unroll
    for (int f = 0; f < 2; ++f)
      qf[qi][f] = *(const bf16x8*)&Qb[(size_t)(q0 + w * 32 + qi * 16 + l16) * HDD + f * 32 + quad * 8];

  fx4 o[2][4];
#pragma unroll
  for (int qi = 0; qi < 2; ++qi)
#pragma unroll
    for (int ht = 0; ht < 4; ++ht) o[qi][ht] = (fx4){0.f, 0.f, 0.f, 0.f};
  float lsum[2] = {0.f, 0.f};

  // staging: 512 chunks of 16B per matrix; 2 per thread; XOR-swizzled placement
  const int cA = tid, cB = 256 + tid;
  const int rA = cA >> 3, pA = (cA & 7) ^ (rA & 7);
  const int rB = cB >> 3, pB = (cB & 7) ^ (rB & 7);

  ix4 rk0 = *(const ix4*)&Kb[(size_t)rA * HDD + pA * 8];
  ix4 rk1 = *(const ix4*)&Kb[(size_t)rB * HDD + pB * 8];
  ix4 rv0 = *(const ix4*)&Vtb[(size_t)rA * SS + pA * 8];
  ix4 rv1 = *(const ix4*)&Vtb[(size_t)rB * SS + pB * 8];
  *(ix4*)((char*)Ks[0] + cA * 16) = rk0;
  *(ix4*)((char*)Ks[0] + cB * 16) = rk1;
  *(ix4*)((char*)Vts[0] + cA * 16) = rv0;
  *(ix4*)((char*)Vts[0] + cB * 16) = rv1;
  __syncthreads();

  for (int k0 = 0; k0 < SS; k0 += 64) {
    const int cur = (k0 >> 6) & 1;
    const bool more = (k0 + 64 < SS);
    if (more) {
      int kn = k0 + 64;
      rk0 = *(const ix4*)&Kb[(size_t)(kn + rA) * HDD + pA * 8];
      rk1 = *(const ix4*)&Kb[(size_t)(kn + rB) * HDD + pB * 8];
      rv0 = *(const ix4*)&Vtb[(size_t)rA * SS + kn + pA * 8];
      rv1 = *(const ix4*)&Vtb[(size_t)rB * SS + kn + pB * 8];
    }
    const unsigned short* KsC = Ks[cur];
    const unsigned short* VtsC = Vts[cur];

    // mask offsets per key (rows of S^T): key = k0 + kt*16 + quad*4 + r
    float4 offn[4];
#pragma unroll
    for (int kt = 0; kt < 4; ++kt) {
      float4 mv = *(const float4*)&mb[k0 + kt * 16 + quad * 4];
      offn[kt].x = fmaf(OFF2, mv.x, -OFF2);
      offn[kt].y = fmaf(OFF2, mv.y, -OFF2);
      offn[kt].z = fmaf(OFF2, mv.z, -OFF2);
      offn[kt].w = fmaf(OFF2, mv.w, -OFF2);
    }

    // K fragments (A-operand: m=key=l16, k=dd natural)
    bf16x8 kf[4][2];
#pragma unroll
    for (int kt = 0; kt < 4; ++kt) {
      int row = kt * 16 + l16;
      int rx = row & 7;
#pragma unroll
      for (int f = 0; f < 2; ++f)
        kf[kt][f] = *(const bf16x8*)&KsC[row * 64 + ((f * 4 + quad) ^ rx) * 8];
    }
    // V fragments (A-operand: m=hd=l16, k-permuted: key=f*32+(j>>2)*16+quad*4+(j&3))
    bf16x8 vf[4][2];
#pragma unroll
    for (int ht = 0; ht < 4; ++ht) {
      int row = ht * 16 + l16;
      int rx = row & 7;
#pragma unroll
      for (int f = 0; f < 2; ++f) {
        int dc0 = (f * 4 + (quad >> 1)) ^ rx;
        int dc1 = (f * 4 + 2 + (quad >> 1)) ^ rx;
        uint2 lo = *(const uint2*)((const char*)VtsC + row * 128 + dc0 * 16 + (quad & 1) * 8);
        uint2 hi = *(const uint2*)((const char*)VtsC + row * 128 + dc1 * 16 + (quad & 1) * 8);
        ix4 vv = (ix4){(int)lo.x, (int)lo.y, (int)hi.x, (int)hi.y};
        vf[ht][f] = __builtin_bit_cast(bf16x8, vv);
      }
    }

#pragma unroll
    for (int qi = 0; qi < 2; ++qi) {
      fx4 sc[4];
#pragma unroll
      for (int kt = 0; kt < 4; ++kt) {
        fx4 s = (fx4){0.f, 0.f, 0.f, 0.f};
        s = MFMA16(kf[kt][0], qf[qi][0], s);
        s = MFMA16(kf[kt][1], qf[qi][1], s);
        sc[kt] = s;
      }
      unsigned pk[4][2];
      float ls = 0.f;
#pragma unroll
      for (int kt = 0; kt < 4; ++kt) {
        const float* offr = (const float*)&offn[kt];
        float p[4];
#pragma unroll
        for (int r = 0; r < 4; ++r)
          p[r] = exp2f(fmaf(sc[kt][r], C2, offr[r]));
        ls += (p[0] + p[1]) + (p[2] + p[3]);
        pk[kt][0] = pkbf(p[0], p[1]);
        pk[kt][1] = pkbf(p[2], p[3]);
      }
      lsum[qi] += ls;
      ix4 p0 = (ix4){(int)pk[0][0], (int)pk[0][1], (int)pk[1][0], (int)pk[1][1]};
      ix4 p1 = (ix4){(int)pk[2][0], (int)pk[2][1], (int)pk[3][0], (int)pk[3][1]};
      bf16x8 pf0 = __builtin_bit_cast(bf16x8, p0);
      bf16x8 pf1 = __builtin_bit_cast(bf16x8, p1);
#pragma unroll
      for (int ht = 0; ht < 4; ++ht) {
        o[qi][ht] = MFMA16(vf[ht][0], pf0, o[qi][ht]);
        o[qi][ht] = MFMA16(vf[ht][1], pf1, o[qi][ht]);
      }
    }

    if (more) {
      *(ix4*)((char*)Ks[cur ^ 1] + cA * 16) = rk0;
      *(ix4*)((char*)Ks[cur ^ 1] + cB * 16) = rk1;
      *(ix4*)((char*)Vts[cur ^ 1] + cA * 16) = rv0;
      *(ix4*)((char*)Vts[cur ^ 1] + cB * 16) = rv1;
    }
    __syncthreads();
  }

#pragma unroll
  for (int qi = 0; qi < 2; ++qi) {
    float t = lsum[qi];
    t += __shfl_xor(t, 16);
    t += __shfl_xor(t, 32);
    float inv = 1.f / fmaxf(t, 1e-30f);
    int sq = q0 + w * 32 + qi * 16 + l16;
    unsigned short* orow = O + ((size_t)(b * SS + sq)) * DD + h * HDD;
#pragma unroll
    for (int ht = 0; ht < 4; ++ht) {
      uint2 v = make_uint2(pkbf(o[qi][ht][0] * inv, o[qi][ht][1] * inv),
                           pkbf(o[qi][ht][2] * inv, o[qi][ht][3] * inv));
      *(uint2*)&orow[ht * 16 + quad * 4] = v;
    }
  }
}

// ---- LayerNorm over D=768: one block per row ----
__global__ __launch_bounds__(256) void ln_k(const float* __restrict__ x,
                                            const float* __restrict__ gamma,
                                            const float* __restrict__ beta,
                                            float* __restrict__ out) {
  const int row = blockIdx.x;
  const float* xr = x + (size_t)row * DD;
  const int t = threadIdx.x;
  float v0 = xr[t], v1 = xr[t + 256], v2 = xr[t + 512];
  float s = v0 + v1 + v2;
  float ss = v0 * v0 + v1 * v1 + v2 * v2;
#pragma unroll
  for (int d = 32; d > 0; d >>= 1) {
    s += __shfl_down(s, d);
    ss += __shfl_down(ss, d);
  }
  __shared__ float sh[10];
  int wv = t >> 6, lane = t & 63;
  if (lane == 0) { sh[wv] = s; sh[4 + wv] = ss; }
  __syncthreads();
  if (t == 0) {
    float S = sh[0] + sh[1] + sh[2] + sh[3];
    float SSm = sh[4] + sh[5] + sh[6] + sh[7];
    float mu = S * (1.0f / DD);
    float var = SSm * (1.0f / DD) - mu * mu;
    sh[8] = mu;
    sh[9] = rsqrtf(var + 1e-5f);
  }
  __syncthreads();
  float mu = sh[8], rstd = sh[9];
  out[(size_t)row * DD + t]       = (v0 - mu) * rstd * gamma[t]       + beta[t];
  out[(size_t)row * DD + t + 256] = (v1 - mu) * rstd * gamma[t + 256] + beta[t + 256];
  out[(size_t)row * DD + t + 512] = (v2 - mu) * rstd * gamma[t + 512] + beta[t + 512];
}

extern "C" void kernel_launch(void* const* d_in, const int* in_sizes, int n_in,
                              void* d_out, int out_size, void* d_ws, size_t ws_size,
                              hipStream_t stream) {
  (void)in_sizes; (void)n_in; (void)out_size; (void)ws_size;
  const float* ctx   = (const float*)d_in[0];
  const float* mask  = (const float*)d_in[1];
  const float* wqkv  = (const float*)d_in[2];
  const float* wproj = (const float*)d_in[3];
  const float* bproj = (const float*)d_in[4];
  const float* gamma = (const float*)d_in[5];
  const float* beta  = (const float*)d_in[6];
  float* out = (float*)d_out;

  char* p = (char*)d_ws;
  unsigned short* Xbf = (unsigned short*)p; p += (size_t)NEL * 2;
  unsigned short* Qw  = (unsigned short*)p; p += (size_t)NEL * 2;
  unsigned short* Kw  = (unsigned short*)p; p += (size_t)NEL * 2;
  unsigned short* Vtw = (unsigned short*)p; p += (size_t)NEL * 2;
  unsigned short* Ao  = (unsigned short*)p; p += (size_t)NEL * 2;
  unsigned short* WqkvT  = (unsigned short*)p; p += (size_t)DD * NQKV * 2;
  unsigned short* WprojT = (unsigned short*)p; p += (size_t)DD * DD * 2;
  float* xf = (float*)Qw;  // reuse Q+K region (attn done before proj writes)

  prep_k<<<NB_PACK + NB_TQKV + NB_TPRJ, 256, 0, stream>>>(ctx, Xbf, wqkv, WqkvT, wproj, WprojT);
  gemm_qkv_k<<<dim3(BS / 128, NQKV / 128), 256, 0, stream>>>(WqkvT, Xbf, Qw, Kw, Vtw);
  attn_k<<<dim3(SS / 128, BB * HH), 256, 0, stream>>>(Qw, Kw, Vtw, mask, Ao);
  gemm_proj_k<<<dim3(BS / 128, DD / 128), 256, 0, stream>>>(WprojT, Ao, ctx, bproj, xf);
  ln_k<<<BS, 256, 0, stream>>>(xf, gamma, beta, out);
}